// Round 5
// baseline (119.310 us; speedup 1.0000x reference)
//
#include <hip/hip_runtime.h>
#include <math.h>

#define DIAG 725
#define HALF 362.0f
#define NIMG 512
#define POFF 106          // data block offset inside padded image
#define PS   736          // padded row stride in ELEMENTS (float or float4)
#define PI_F 3.14159265358979323846f

// padded-image value: zero outside central 512x512 data block
__device__ inline float pval(const float* __restrict__ img, int y, int x)
{
    const int dr = y - POFF, dc = x - POFF;
    return ((unsigned)dr < (unsigned)NIMG && (unsigned)dc < (unsigned)NIMG)
               ? img[dr * NIMG + dc] : 0.0f;
}

// ---- build quad + quadT: quad[y][x] = (p(y,x), p(y,x+1), p(y+1,x), p(y+1,x+1))
// Tiled through LDS so both orientations write coalesced.
__global__ __launch_bounds__(256) void build_quads(const float* __restrict__ img,
                                                   float4* __restrict__ quad,
                                                   float4* __restrict__ quadT)
{
    __shared__ float s[65][66];
    const int tid = (int)threadIdx.x, lane = tid & 63, grp = tid >> 6;
    const int x0 = (int)blockIdx.x * 64, y0 = (int)blockIdx.y * 64;

    for (int i = grp; i < 65; i += 4) {
        s[i][lane] = pval(img, y0 + i, x0 + lane);
        if (lane == 0) s[i][64] = pval(img, y0 + i, x0 + 64);
    }
    __syncthreads();

    for (int n = tid; n < 64 * 64; n += 256) {        // pad-quad, j fast
        const int i = n >> 6, j = n & 63;
        const int gy = y0 + i, gx = x0 + j;
        if (gy < DIAG && gx < DIAG)
            quad[gy * PS + gx] = make_float4(s[i][j], s[i][j + 1],
                                             s[i + 1][j], s[i + 1][j + 1]);
    }
    for (int n = tid; n < 64 * 64; n += 256) {        // padT-quad, j fast
        const int i = n >> 6, j = n & 63;
        const int gu = x0 + i, gv = y0 + j;           // pT(u,v) = p(v,u)
        if (gu < DIAG && gv < DIAG)
            quadT[gu * PS + gv] = make_float4(s[j][i], s[j + 1][i],
                                              s[j][i + 1], s[j + 1][i + 1]);
    }
}

// Per-angle trig table: {ct, st, 1/ct (0 if tiny), 1/st (0 if tiny)}.
__global__ __launch_bounds__(256) void trig_kernel(const float* __restrict__ angles,
                                                   int n_ang, float4* __restrict__ tbl)
{
    const int a = blockIdx.x * 256 + threadIdx.x;
    if (a >= n_ang) return;
    const float rad = -angles[a] * (PI_F / 180.0f);
    const float ct = cosf(rad), st = sinf(rad);
    tbl[a] = make_float4(ct, st,
                         (fabsf(ct) > 1e-4f) ? 1.0f / ct : 0.0f,
                         (fabsf(st) > 1e-4f) ? 1.0f / st : 0.0f);
}

// One float4 load per bilinear sample.
__device__ inline float samp_quad(const float4* __restrict__ q, float X, float Y)
{
    const float fx = floorf(X), fy = floorf(Y);
    const float ax = X - fx,  ay = Y - fy;
    const int idx = (int)fmaf(fy, (float)PS, fx);     // exact: < 2^24
    const float4 v = q[idx];
    const float top = fmaf(ax, v.y - v.x, v.x);
    const float bot = fmaf(ax, v.w - v.z, v.z);
    return fmaf(ay, bot - top, top);
}

// One wave per (angle a, sinogram row r); lanes stride c.
__global__ __launch_bounds__(256) void radon_quad(const float4* __restrict__ quad,
                                                  const float4* __restrict__ quadT,
                                                  const float4* __restrict__ tbl,
                                                  float* __restrict__ out, int n_ang)
{
    const int wib = (int)(threadIdx.x >> 6);
    const int lane = (int)(threadIdx.x & 63);
    const int w = (int)blockIdx.x * 4 + wib;
    const int a = w / DIAG;
    const int r = w - a * DIAG;
    if (a >= n_ang) return;

    const float4 t = tbl[a];
    const float ct = t.x, st = t.y, rct = t.z, rst = t.w;

    const float dy = (float)r - HALF;
    const float Bx = HALF - HALF * ct - st * dy;   // x(c) = ct*c + Bx
    const float By = HALF - HALF * st + ct * dy;   // y(c) = st*c + By

    float lo = 0.0f, hi = 724.0f;
    if (rct != 0.0f) {
        const float c1 = (104.0f - Bx) * rct, c2 = (619.0f - Bx) * rct;
        lo = fmaxf(lo, fminf(c1, c2)); hi = fminf(hi, fmaxf(c1, c2));
    } else if (Bx < 103.0f || Bx > 620.0f) { hi = -1.0f; }
    if (rst != 0.0f) {
        const float c1 = (104.0f - By) * rst, c2 = (619.0f - By) * rst;
        lo = fmaxf(lo, fminf(c1, c2)); hi = fminf(hi, fmaxf(c1, c2));
    } else if (By < 103.0f || By > 620.0f) { hi = -1.0f; }

    int nfull = 0, tail = 0, clo = 0, chi = 0;
    if (hi >= lo) {
        clo = (int)fmaxf(0.0f, floorf(lo));
        chi = (int)fminf(724.0f, ceilf(hi));
        const int len = chi - clo + 1;
        if (len > 0) { nfull = len >> 6; tail = len & 63; }
    }

    const bool useT = fabsf(st) > fabsf(ct);
    const float4* q = useT ? quadT : quad;
    const float cF = useT ? st : ct;
    const float cS = useT ? ct : st;
    const float bF = useT ? By : Bx;
    const float bS = useT ? Bx : By;

    float fc = (float)(clo + lane);
    float s0 = 0.0f, s1 = 0.0f;
    int k = 0;
    for (; k + 2 <= nfull; k += 2) {
        s0 += samp_quad(q, fmaf(cF, fc, bF),         fmaf(cS, fc, bS));
        s1 += samp_quad(q, fmaf(cF, fc + 64.0f, bF), fmaf(cS, fc + 64.0f, bS));
        fc += 128.0f;
    }
    if (k < nfull) {
        s0 += samp_quad(q, fmaf(cF, fc, bF), fmaf(cS, fc, bS));
        fc += 64.0f;
    }
    if (tail) {
        const float val = samp_quad(q, fmaf(cF, fc, bF), fmaf(cS, fc, bS));
        s1 += (fc <= (float)chi) ? val : 0.0f;
    }

    float sum = s0 + s1;
    #pragma unroll
    for (int off = 32; off > 0; off >>= 1)
        sum += __shfl_down(sum, off);
    if (lane == 0)
        out[r * n_ang + a] = sum;
}

// ---------------- legacy scalar fallback (proven R3 path) -------------------
__global__ __launch_bounds__(256) void pad_kernel(const float* __restrict__ img,
                                                  float* __restrict__ pad,
                                                  float* __restrict__ padT)
{
    const int col = blockIdx.x * 256 + threadIdx.x;
    const int row = blockIdx.y;
    if (col >= PS) return;
    const float v = pval(img, row, col);
    pad[row * PS + col] = v;
    if (col < DIAG && padT) padT[col * PS + row] = v;
}

__device__ inline float sample_nc(const float* __restrict__ p0, float X, float Y)
{
    const float fx = floorf(X), fy = floorf(Y);
    const float ax = X - fx,  ay = Y - fy;
    const int idx = (int)fmaf(fy, (float)PS, fx);
    const float* p = p0 + idx;
    const float Ia = p[0], Ib = p[1], Ic = p[PS], Id = p[PS + 1];
    const float top = fmaf(ax, Ib - Ia, Ia);
    const float bot = fmaf(ax, Id - Ic, Ic);
    return fmaf(ay, bot - top, top);
}

__global__ __launch_bounds__(256) void radon_uni(const float* __restrict__ pad,
                                                 const float* __restrict__ padT,
                                                 const float4* __restrict__ tbl,
                                                 float* __restrict__ out, int n_ang)
{
    const int wib = (int)(threadIdx.x >> 6);
    const int lane = (int)(threadIdx.x & 63);
    const int w = (int)blockIdx.x * 4 + wib;
    const int a = w / DIAG;
    const int r = w - a * DIAG;
    if (a >= n_ang) return;

    const float4 t = tbl[a];
    const float ct = t.x, st = t.y, rct = t.z, rst = t.w;
    const float dy = (float)r - HALF;
    const float Bx = HALF - HALF * ct - st * dy;
    const float By = HALF - HALF * st + ct * dy;

    float lo = 0.0f, hi = 724.0f;
    if (rct != 0.0f) {
        const float c1 = (104.0f - Bx) * rct, c2 = (619.0f - Bx) * rct;
        lo = fmaxf(lo, fminf(c1, c2)); hi = fminf(hi, fmaxf(c1, c2));
    } else if (Bx < 103.0f || Bx > 620.0f) { hi = -1.0f; }
    if (rst != 0.0f) {
        const float c1 = (104.0f - By) * rst, c2 = (619.0f - By) * rst;
        lo = fmaxf(lo, fminf(c1, c2)); hi = fminf(hi, fmaxf(c1, c2));
    } else if (By < 103.0f || By > 620.0f) { hi = -1.0f; }

    int nfull = 0, tail = 0, clo = 0, chi = 0;
    if (hi >= lo) {
        clo = (int)fmaxf(0.0f, floorf(lo));
        chi = (int)fminf(724.0f, ceilf(hi));
        const int len = chi - clo + 1;
        if (len > 0) { nfull = len >> 6; tail = len & 63; }
    }

    const bool useT = (fabsf(st) > fabsf(ct)) && (padT != nullptr);
    const float* imgp = useT ? padT : pad;
    const float cF = useT ? st : ct;
    const float cS = useT ? ct : st;
    const float bF = useT ? By : Bx;
    const float bS = useT ? Bx : By;

    float fc = (float)(clo + lane);
    float s0 = 0.0f, s1 = 0.0f;
    int k = 0;
    for (; k + 2 <= nfull; k += 2) {
        s0 += sample_nc(imgp, fmaf(cF, fc, bF),         fmaf(cS, fc, bS));
        s1 += sample_nc(imgp, fmaf(cF, fc + 64.0f, bF), fmaf(cS, fc + 64.0f, bS));
        fc += 128.0f;
    }
    if (k < nfull) {
        s0 += sample_nc(imgp, fmaf(cF, fc, bF), fmaf(cS, fc, bS));
        fc += 64.0f;
    }
    if (tail) {
        const float val = sample_nc(imgp, fmaf(cF, fc, bF), fmaf(cS, fc, bS));
        s1 += (fc <= (float)chi) ? val : 0.0f;
    }

    float sum = s0 + s1;
    #pragma unroll
    for (int off = 32; off > 0; off >>= 1)
        sum += __shfl_down(sum, off);
    if (lane == 0)
        out[r * n_ang + a] = sum;
}

extern "C" void kernel_launch(void* const* d_in, const int* in_sizes, int n_in,
                              void* d_out, int out_size, void* d_ws, size_t ws_size,
                              hipStream_t stream) {
    const float* img = (const float*)d_in[0];
    const float* angles = (const float*)d_in[1];
    float* out = (float*)d_out;
    const int n_ang = in_sizes[1];

    const size_t img_e = (size_t)DIAG * PS;                 // elements per image
    const size_t quad_b = img_e * sizeof(float4);           // 8,537,600 B
    const size_t tbl_b = (size_t)((n_ang + 255) & ~255) * sizeof(float4);
    const int waves = n_ang * DIAG;

    if (ws_size >= 2 * quad_b + tbl_b) {
        float4* quad  = (float4*)d_ws;
        float4* quadT = quad + img_e;
        float4* tbl   = quadT + img_e;
        build_quads<<<dim3(12, 12), 256, 0, stream>>>(img, quad, quadT);
        trig_kernel<<<(n_ang + 255) / 256, 256, 0, stream>>>(angles, n_ang, tbl);
        radon_quad<<<(waves + 3) / 4, 256, 0, stream>>>(quad, quadT, tbl, out, n_ang);
    } else {
        float* pad = (float*)d_ws;
        float4* tbl = (float4*)(pad + img_e);
        float* padT_cand = (float*)tbl + (tbl_b / sizeof(float));
        const size_t need_T = (2 * img_e) * sizeof(float) + tbl_b;
        float* padT = (ws_size >= need_T) ? padT_cand : nullptr;
        pad_kernel<<<dim3(3, DIAG), 256, 0, stream>>>(img, pad, padT);
        trig_kernel<<<(n_ang + 255) / 256, 256, 0, stream>>>(angles, n_ang, tbl);
        radon_uni<<<(waves + 3) / 4, 256, 0, stream>>>(pad, padT, tbl, out, n_ang);
    }
}

// Round 6
// 104.853 us; speedup vs baseline: 1.1379x; 1.1379x over previous
//
#include <hip/hip_runtime.h>
#include <hip/hip_fp16.h>
#include <math.h>

#define DIAG 725
#define HALF 362.0f
#define NIMG 512
#define PW   536          // sampling-window size (padded coords [96, 632))
#define WOFF 96           // window offset in padded coords
#define NBAND 91          // ceil(725/8) row-bands of 8
#define PI_F 3.14159265358979323846f

// padded-image value: zero outside central 512x512 data block (data at [106,618))
__device__ inline float pval(const float* __restrict__ img, int y, int x)
{
    const int dr = y - 106, dc = x - 106;
    return ((unsigned)dr < (unsigned)NIMG && (unsigned)dc < (unsigned)NIMG)
               ? img[dr * NIMG + dc] : 0.0f;
}

// pairX [y'][x'] = half2( p(y'+96, x'+96), p(y'+96, x'+96+1) )   (pairs along x)
// pairXT[u'][v'] = half2( p(v'+96, u'+96), p(v'+96+1, u'+96) )   (transposed frame,
//                  pairs along its own fast coord v' = y)
__global__ __launch_bounds__(256) void build_pairs(const float* __restrict__ img,
                                                   __half2* __restrict__ pairX,
                                                   __half2* __restrict__ pairXT)
{
    __shared__ float s[65][66];
    const int tid = (int)threadIdx.x, lane = tid & 63, grp = tid >> 6;
    const int x0 = (int)blockIdx.x * 64, y0 = (int)blockIdx.y * 64;

    for (int i = grp; i < 65; i += 4) {
        s[i][lane] = pval(img, y0 + WOFF + i, x0 + WOFF + lane);
        if (lane == 0) s[i][64] = pval(img, y0 + WOFF + i, x0 + WOFF + 64);
    }
    __syncthreads();

    for (int n = tid; n < 4096; n += 256) {
        const int i = n >> 6, j = n & 63;
        const int gy = y0 + i, gx = x0 + j;
        if (gy < PW && gx < PW)
            pairX[gy * PW + gx] = __floats2half2_rn(s[i][j], s[i][j + 1]);
        const int u = x0 + i, v = y0 + j;         // pairXT[u][v] = (p(v,u), p(v+1,u))
        if (u < PW && v < PW)
            pairXT[u * PW + v] = __floats2half2_rn(s[j][i], s[j + 1][i]);
    }
}

// Per-angle trig table: {ct, st, 1/ct (0 if tiny), 1/st (0 if tiny)}.
__global__ __launch_bounds__(256) void trig_kernel(const float* __restrict__ angles,
                                                   int n_ang, float4* __restrict__ tbl)
{
    const int a = blockIdx.x * 256 + threadIdx.x;
    if (a >= n_ang) return;
    const float rad = -angles[a] * (PI_F / 180.0f);
    const float ct = cosf(rad), st = sinf(rad);
    tbl[a] = make_float4(ct, st,
                         (fabsf(ct) > 1e-4f) ? 1.0f / ct : 0.0f,
                         (fabsf(st) > 1e-4f) ? 1.0f / st : 0.0f);
}

// 2D-tiled radon: one wave handles 8 rows x (c-range in steps of 8).
// lane = ri*8 + ci ; sample (r0+ri, c = base + it*8 + ci).
// grid: (chunk=2, band-groups=23, angle)
__global__ __launch_bounds__(256) void radon2d(const __half2* __restrict__ pairX,
                                               const __half2* __restrict__ pairXT,
                                               const float4* __restrict__ tbl,
                                               float* __restrict__ partial, int n_ang)
{
    const int tid = (int)threadIdx.x;
    const int wib = tid >> 6, lane = tid & 63;
    const int ci = lane & 7, ri = lane >> 3;
    const int a = (int)blockIdx.z;
    const int chunk = (int)blockIdx.x;
    const int band = (int)blockIdx.y * 4 + wib;
    if (band >= NBAND) return;

    const int r = band * 8 + ri;
    const int rc = (r < DIAG) ? r : (DIAG - 1);

    const float4 t = tbl[a];
    const float ct = t.x, st = t.y, rct = t.z, rst = t.w;
    const float dy = (float)rc - HALF;
    const float Bx = HALF - HALF * ct - st * dy;   // x(c) = ct*c + Bx (padded coords)
    const float By = HALF - HALF * st + ct * dy;   // y(c) = st*c + By

    // per-row c-interval where footprint can touch the data block
    float lo = 0.0f, hi = 724.0f;
    if (rct != 0.0f) {
        const float c1 = (104.0f - Bx) * rct, c2 = (619.0f - Bx) * rct;
        lo = fmaxf(lo, fminf(c1, c2)); hi = fminf(hi, fmaxf(c1, c2));
    } else if (Bx < 103.0f || Bx > 620.0f) { hi = -1.0f; }
    if (rst != 0.0f) {
        const float c1 = (104.0f - By) * rst, c2 = (619.0f - By) * rst;
        lo = fmaxf(lo, fminf(c1, c2)); hi = fminf(hi, fmaxf(c1, c2));
    } else if (By < 103.0f || By > 620.0f) { hi = -1.0f; }

    int clo_r = 0x7fffffff, chi_r = -0x7fffffff;
    if (hi >= lo) {
        clo_r = (int)fmaxf(0.0f, floorf(lo));
        chi_r = (int)fminf(724.0f, ceilf(hi));
    }

    // wave-wide union of the 8 rows' ranges
    int cloU = clo_r, chiU = chi_r;
    #pragma unroll
    for (int m = 1; m < 64; m <<= 1) {
        cloU = min(cloU, __shfl_xor(cloU, m));
        chiU = max(chiU, __shfl_xor(chiU, m));
    }

    int n8 = 0;
    if (chiU >= cloU) n8 = (chiU - cloU + 8) >> 3;   // ceil(len/8)
    const int h = (n8 + 1) >> 1;
    const int s_it = chunk ? h : 0;
    const int e_it = chunk ? n8 : h;

    // frame: fast coordinate = larger |step|
    const bool useT = fabsf(st) > fabsf(ct);
    const __half2* q = useT ? pairXT : pairX;
    const float cF = useT ? st : ct;
    const float cS = useT ? ct : st;
    const float bF = (useT ? By : Bx) - (float)WOFF;
    const float bS = (useT ? Bx : By) - (float)WOFF;

    float fc = (float)(cloU + s_it * 8 + ci);
    float s0 = 0.0f, s1 = 0.0f;

    #define SAMPLE(acc, fcv)                                                    \
    {                                                                           \
        const float X = fmaf(cF, (fcv), bF);                                    \
        const float Y = fmaf(cS, (fcv), bS);                                    \
        const float fx = floorf(X), fy = floorf(Y);                             \
        const float ax = X - fx, ay = Y - fy;                                   \
        const bool vld = (fx >= 0.0f) & (fx <= 533.0f) &                        \
                         (fy >= 0.0f) & (fy <= 533.0f) & ((fcv) <= 724.5f);     \
        int idx = (int)fmaf(fy, (float)PW, fx);                                 \
        idx = vld ? idx : 0;                                                    \
        const float2 L = __half22float2(q[idx]);                                \
        const float2 H = __half22float2(q[idx + PW]);                           \
        const float top = fmaf(ax, L.y - L.x, L.x);                             \
        const float bot = fmaf(ax, H.y - H.x, H.x);                             \
        acc += fmaf(ay, bot - top, top);                                        \
    }

    int it = s_it;
    for (; it + 2 <= e_it; it += 2) {
        SAMPLE(s0, fc)
        SAMPLE(s1, fc + 8.0f)
        fc += 16.0f;
    }
    if (it < e_it)
        SAMPLE(s0, fc)
    #undef SAMPLE

    float sum = s0 + s1;
    sum += __shfl_xor(sum, 1);
    sum += __shfl_xor(sum, 2);
    sum += __shfl_xor(sum, 4);

    if (ci == 0 && r < DIAG)
        partial[chunk * (DIAG * 180) + r * n_ang + a] = sum;
}

__global__ __launch_bounds__(256) void combine_kernel(const float* __restrict__ partial,
                                                      float* __restrict__ out, int n)
{
    const int i = blockIdx.x * 256 + threadIdx.x;
    if (i < n) out[i] = partial[i] + partial[DIAG * 180 + i];
}

extern "C" void kernel_launch(void* const* d_in, const int* in_sizes, int n_in,
                              void* d_out, int out_size, void* d_ws, size_t ws_size,
                              hipStream_t stream) {
    const float* img = (const float*)d_in[0];
    const float* angles = (const float*)d_in[1];
    float* out = (float*)d_out;
    const int n_ang = in_sizes[1];

    const size_t pair_e = (size_t)PW * PW;                    // 287,296 half2
    __half2* pairX  = (__half2*)d_ws;
    __half2* pairXT = pairX + pair_e;
    float4*  tbl    = (float4*)(pairXT + pair_e);
    float*   partial = (float*)(tbl + 256);                   // 2 * 725*180 floats

    build_pairs<<<dim3(9, 9), 256, 0, stream>>>(img, pairX, pairXT);
    trig_kernel<<<(n_ang + 255) / 256, 256, 0, stream>>>(angles, n_ang, tbl);

    radon2d<<<dim3(2, (NBAND + 3) / 4, n_ang), 256, 0, stream>>>(pairX, pairXT, tbl,
                                                                 partial, n_ang);

    const int n = DIAG * n_ang;
    combine_kernel<<<(n + 255) / 256, 256, 0, stream>>>(partial, out, n);
}